// Round 1
// baseline (37.223 us; speedup 1.0000x reference)
//
#include <hip/hip_runtime.h>
#include <math.h>

// Problem constants (B=8, N=M=4096, D=2)
#define NPTS   4096
#define NBATCH 8
#define BQ     256          // queries per block
#define SLOTS  128          // query slots per chunk-group (R=2 queries/slot)
#define NS     8            // loop-split chunks per block
#define CHUNK  (NPTS / NS)  // 512 stream points per chunk

__global__ __launch_bounds__(1024) void chamfer_main(
    const float* __restrict__ x, const float* __restrict__ tgt,
    float* __restrict__ partials)
{
    // 4096 stream points as (tx, ty, |t|^2, pad) = 64 KB
    __shared__ float4 sm[NPTS];

    const int bx  = blockIdx.x;
    const int dir = bx >> 7;          // 0: queries=x stream=target, 1: swapped
    const int b   = (bx >> 4) & 7;
    const int qt  = bx & 15;
    const int tid = threadIdx.x;

    const float* qarr = dir ? tgt : x;
    const float* sarr = dir ? x   : tgt;

    // ---- stage stream points + squared norms into LDS ----
    const float4* sp4 = (const float4*)(sarr + b * (NPTS * 2));
    for (int k = tid; k < NPTS / 2; k += 1024) {
        float4 two = sp4[k];  // two packed float2 points
        sm[2 * k]     = make_float4(two.x, two.y, fmaf(two.x, two.x, two.y * two.y), 0.f);
        sm[2 * k + 1] = make_float4(two.z, two.w, fmaf(two.z, two.z, two.w * two.w), 0.f);
    }

    // ---- per-thread query setup (R=2 queries per slot) ----
    const int slot  = tid & (SLOTS - 1);
    const int s     = tid >> 7;       // chunk id 0..7 (wave-uniform: 64 | 128)
    const int qbase = qt * BQ;
    const float2* qp = (const float2*)(qarr + b * (NPTS * 2));
    const float2 p0 = qp[qbase + slot];
    const float2 p1 = qp[qbase + slot + SLOTS];
    const float nx0 = -2.f * p0.x, ny0 = -2.f * p0.y;
    const float nx1 = -2.f * p1.x, ny1 = -2.f * p1.y;
    const float pp0 = fmaf(p0.x, p0.x, p0.y * p0.y);
    const float pp1 = fmaf(p1.x, p1.x, p1.y * p1.y);

    __syncthreads();

    // ---- inner loop: min over this thread's 512-point chunk ----
    const float4* tp = sm + s * CHUNK;
    float m00 = INFINITY, m01 = INFINITY, m02 = INFINITY, m03 = INFINITY;
    float m10 = INFINITY, m11 = INFINITY, m12 = INFINITY, m13 = INFINITY;
    for (int j = 0; j < CHUNK; j += 4) {
        const float4 t0 = tp[j + 0];
        const float4 t1 = tp[j + 1];
        const float4 t2 = tp[j + 2];
        const float4 t3 = tp[j + 3];
        m00 = fminf(m00, fmaf(nx0, t0.x, fmaf(ny0, t0.y, t0.z)));
        m01 = fminf(m01, fmaf(nx0, t1.x, fmaf(ny0, t1.y, t1.z)));
        m02 = fminf(m02, fmaf(nx0, t2.x, fmaf(ny0, t2.y, t2.z)));
        m03 = fminf(m03, fmaf(nx0, t3.x, fmaf(ny0, t3.y, t3.z)));
        m10 = fminf(m10, fmaf(nx1, t0.x, fmaf(ny1, t0.y, t0.z)));
        m11 = fminf(m11, fmaf(nx1, t1.x, fmaf(ny1, t1.y, t1.z)));
        m12 = fminf(m12, fmaf(nx1, t2.x, fmaf(ny1, t2.y, t2.z)));
        m13 = fminf(m13, fmaf(nx1, t3.x, fmaf(ny1, t3.y, t3.z)));
    }
    const float mA = fminf(fminf(m00, m01), fminf(m02, m03));
    const float mB = fminf(fminf(m10, m11), fminf(m12, m13));
    // clamp in d2-space (monotone, so min of clamped == clamped min)
    const float d2A = fmaxf(mA + pp0, 0.f);
    const float d2B = fmaxf(mB + pp1, 0.f);

    // ---- combine chunk partials within the block (reuse LDS) ----
    __syncthreads();  // everyone done reading stream points
    float* mins = (float*)sm;  // NS * BQ = 2048 floats
    mins[s * BQ + slot]         = d2A;
    mins[s * BQ + slot + SLOTS] = d2B;
    __syncthreads();

    float dval = 0.f;
    if (tid < BQ) {
        float m = mins[tid];
        #pragma unroll
        for (int ss = 1; ss < NS; ++ss) m = fminf(m, mins[ss * BQ + tid]);
        dval = sqrtf(m);
    }
    __syncthreads();
    float* red = (float*)sm;
    if (tid < BQ) red[tid] = dval;
    __syncthreads();
    if (tid < 64) {
        float v = red[tid] + red[tid + 64] + red[tid + 128] + red[tid + 192];
        v += __shfl_down(v, 32);
        v += __shfl_down(v, 16);
        v += __shfl_down(v, 8);
        v += __shfl_down(v, 4);
        v += __shfl_down(v, 2);
        v += __shfl_down(v, 1);
        if (tid == 0) partials[blockIdx.x] = v;
    }
}

__global__ __launch_bounds__(256) void chamfer_final(
    const float* __restrict__ partials, float* __restrict__ out)
{
    __shared__ float red[256];
    const int tid = threadIdx.x;
    red[tid] = partials[tid];
    __syncthreads();
    if (tid < 64) {
        float v = red[tid] + red[tid + 64] + red[tid + 128] + red[tid + 192];
        v += __shfl_down(v, 32);
        v += __shfl_down(v, 16);
        v += __shfl_down(v, 8);
        v += __shfl_down(v, 4);
        v += __shfl_down(v, 2);
        v += __shfl_down(v, 1);
        // mean(d_t_to_x) + mean(d_x_to_t): both halves divide by B*4096 = 32768
        if (tid == 0) out[0] = v * (1.0f / 32768.0f);
    }
}

extern "C" void kernel_launch(void* const* d_in, const int* in_sizes, int n_in,
                              void* d_out, int out_size, void* d_ws, size_t ws_size,
                              hipStream_t stream) {
    const float* x   = (const float*)d_in[0];
    const float* tgt = (const float*)d_in[1];
    float* partials  = (float*)d_ws;   // 256 floats
    float* out       = (float*)d_out;  // 1 float

    chamfer_main<<<dim3(256), dim3(1024), 0, stream>>>(x, tgt, partials);
    chamfer_final<<<dim3(1), dim3(256), 0, stream>>>(partials, out);
}

// Round 2
// 24.606 us; speedup vs baseline: 1.5127x; 1.5127x over previous
//
#include <hip/hip_runtime.h>
#include <math.h>

// Problem constants (B=8, N=M=4096, D=2)
#define NPTS   4096
#define BQ     256           // queries per block
#define RQ     8             // queries per thread
#define SLOTS  (BQ / RQ)     // 32 threads span the query tile
#define NS     (1024 / SLOTS)// 32 chunk groups
#define CHUNK  (NPTS / NS)   // 128 stream points per chunk

__global__ __launch_bounds__(1024) void chamfer_main(
    const float* __restrict__ x, const float* __restrict__ tgt,
    float* __restrict__ partials)
{
    __shared__ float4 sm[NPTS / 2];   // 4096 raw float2 points packed, 32 KB
    __shared__ float  mins[NS * BQ];  // 32 KB partial mins (d2 incl. query norm)

    const int bx  = blockIdx.x;
    const int dir = bx >> 7;          // 0: queries=x stream=target, 1: swapped
    const int b   = (bx >> 4) & 7;
    const int qt  = bx & 15;
    const int tid = threadIdx.x;

    const float* qarr = dir ? tgt : x;
    const float* sarr = dir ? x   : tgt;

    // ---- stage raw stream points into LDS (2 float2 per float4) ----
    const float4* sp4 = (const float4*)(sarr + b * (NPTS * 2));
    for (int k = tid; k < NPTS / 2; k += 1024) sm[k] = sp4[k];

    // ---- per-thread query setup: RQ=8 queries in registers ----
    const int slot = tid & (SLOTS - 1);
    const int s    = tid >> 5;        // chunk id 0..31
    const float2* qp = (const float2*)(qarr + b * (NPTS * 2));
    float nx[RQ], ny[RQ], pp[RQ], m[RQ];
    #pragma unroll
    for (int r = 0; r < RQ; ++r) {
        const float2 p = qp[qt * BQ + slot + r * SLOTS];
        nx[r] = -2.f * p.x;
        ny[r] = -2.f * p.y;
        pp[r] = fmaf(p.x, p.x, p.y * p.y);
        m[r]  = INFINITY;
    }

    __syncthreads();

    // ---- inner loop: 1 ds_read_b128 (2 points) per 52 VALU insts ----
    const float4* tp = sm + s * (CHUNK / 2);
    #pragma unroll 4
    for (int j = 0; j < CHUNK / 2; ++j) {
        const float4 t = tp[j];
        const float z0 = fmaf(t.x, t.x, t.y * t.y);
        const float z1 = fmaf(t.z, t.z, t.w * t.w);
        #pragma unroll
        for (int r = 0; r < RQ; ++r) {
            m[r] = fminf(m[r], fmaf(nx[r], t.x, fmaf(ny[r], t.y, z0)));
            m[r] = fminf(m[r], fmaf(nx[r], t.z, fmaf(ny[r], t.w, z1)));
        }
    }

    // fold query norm into the partial (constant across chunks: min(m)+pp == min(m+pp))
    #pragma unroll
    for (int r = 0; r < RQ; ++r)
        mins[s * BQ + slot + r * SLOTS] = m[r] + pp[r];
    __syncthreads();

    // ---- cross-chunk min + sqrt, then block sum ----
    float dval = 0.f;
    if (tid < BQ) {
        float mm = mins[tid];
        #pragma unroll
        for (int ss = 1; ss < NS; ++ss) mm = fminf(mm, mins[ss * BQ + tid]);
        dval = sqrtf(fmaxf(mm, 0.f));
    }
    __syncthreads();
    float* red = (float*)sm;
    if (tid < BQ) red[tid] = dval;
    __syncthreads();
    if (tid < 64) {
        float v = red[tid] + red[tid + 64] + red[tid + 128] + red[tid + 192];
        v += __shfl_down(v, 32);
        v += __shfl_down(v, 16);
        v += __shfl_down(v, 8);
        v += __shfl_down(v, 4);
        v += __shfl_down(v, 2);
        v += __shfl_down(v, 1);
        if (tid == 0) partials[blockIdx.x] = v;
    }
}

__global__ __launch_bounds__(256) void chamfer_final(
    const float* __restrict__ partials, float* __restrict__ out)
{
    __shared__ float red[256];
    const int tid = threadIdx.x;
    red[tid] = partials[tid];
    __syncthreads();
    if (tid < 64) {
        float v = red[tid] + red[tid + 64] + red[tid + 128] + red[tid + 192];
        v += __shfl_down(v, 32);
        v += __shfl_down(v, 16);
        v += __shfl_down(v, 8);
        v += __shfl_down(v, 4);
        v += __shfl_down(v, 2);
        v += __shfl_down(v, 1);
        // mean(d_t_to_x) + mean(d_x_to_t): both halves divide by B*4096 = 32768
        if (tid == 0) out[0] = v * (1.0f / 32768.0f);
    }
}

extern "C" void kernel_launch(void* const* d_in, const int* in_sizes, int n_in,
                              void* d_out, int out_size, void* d_ws, size_t ws_size,
                              hipStream_t stream) {
    const float* x   = (const float*)d_in[0];
    const float* tgt = (const float*)d_in[1];
    float* partials  = (float*)d_ws;   // 256 floats
    float* out       = (float*)d_out;  // 1 float

    chamfer_main<<<dim3(256), dim3(1024), 0, stream>>>(x, tgt, partials);
    chamfer_final<<<dim3(1), dim3(256), 0, stream>>>(partials, out);
}

// Round 3
// 23.423 us; speedup vs baseline: 1.5891x; 1.0505x over previous
//
#include <hip/hip_runtime.h>
#include <math.h>

// Problem constants (B=8, N=M=4096, D=2)
#define NPTS   4096
#define BQ     128            // queries per block (grid 512 -> 2 blocks/CU)
#define RQ     8              // queries per thread
#define SLOTS  (BQ / RQ)      // 16 threads span the query tile
#define NS     (1024 / SLOTS) // 64 chunk groups
#define CHUNK  (NPTS / NS)    // 64 stream points per chunk

__global__ __launch_bounds__(1024, 8) void chamfer_main(
    const float* __restrict__ x, const float* __restrict__ tgt,
    float* __restrict__ partials)
{
    __shared__ float4 sm[NPTS / 2];   // 4096 raw float2 points packed, 32 KB
    __shared__ float  mins[NS * BQ];  // 64*128 partial mins, 32 KB

    const int bx  = blockIdx.x;
    const int dir = bx >> 8;          // 0: queries=x stream=target, 1: swapped
    const int b   = (bx >> 5) & 7;
    const int qt  = bx & 31;          // 32 query tiles of 128
    const int tid = threadIdx.x;

    const float* qarr = dir ? tgt : x;
    const float* sarr = dir ? x   : tgt;

    // ---- stage raw stream points into LDS (2 float2 per float4) ----
    const float4* sp4 = (const float4*)(sarr + b * (NPTS * 2));
    sm[tid]        = sp4[tid];
    sm[tid + 1024] = sp4[tid + 1024];

    // ---- per-thread query setup: RQ=8 queries in registers ----
    const int slot = tid & (SLOTS - 1);
    const int s    = tid >> 4;        // chunk id 0..63
    const float2* qp = (const float2*)(qarr + b * (NPTS * 2));
    float nx[RQ], ny[RQ], m[RQ];
    #pragma unroll
    for (int r = 0; r < RQ; ++r) {
        const float2 p = qp[qt * BQ + slot + r * SLOTS];
        nx[r] = -2.f * p.x;
        ny[r] = -2.f * p.y;
        m[r]  = INFINITY;
    }

    __syncthreads();

    // ---- inner loop: 1 ds_read_b128 (2 points) -> 44 VALU (min3-fused) ----
    const float4* tp = sm + s * (CHUNK / 2);
    #pragma unroll 2
    for (int j = 0; j < CHUNK / 2; ++j) {
        const float4 t = tp[j];
        const float z0 = fmaf(t.x, t.x, t.y * t.y);
        const float z1 = fmaf(t.z, t.z, t.w * t.w);
        #pragma unroll
        for (int r = 0; r < RQ; ++r) {
            const float d0 = fmaf(nx[r], t.x, fmaf(ny[r], t.y, z0));
            const float d1 = fmaf(nx[r], t.z, fmaf(ny[r], t.w, z1));
            m[r] = fminf(fminf(m[r], d0), d1);   // -> v_min3_f32
        }
    }

    // fold query norm (rematerialized from nx,ny to save loop registers)
    #pragma unroll
    for (int r = 0; r < RQ; ++r) {
        const float pp = 0.25f * fmaf(nx[r], nx[r], ny[r] * ny[r]);
        mins[s * BQ + slot + r * SLOTS] = m[r] + pp;
    }
    __syncthreads();

    // ---- cross-chunk min + sqrt, then block sum ----
    float dval = 0.f;
    if (tid < BQ) {
        float mm = mins[tid];
        #pragma unroll
        for (int ss = 1; ss < NS; ++ss) mm = fminf(mm, mins[ss * BQ + tid]);
        dval = sqrtf(fmaxf(mm, 0.f));
    }
    float* red = (float*)sm;  // safe: all sm reads completed before prior sync
    if (tid < BQ) red[tid] = dval;
    __syncthreads();
    if (tid < 64) {
        float v = red[tid] + red[tid + 64];
        v += __shfl_down(v, 32);
        v += __shfl_down(v, 16);
        v += __shfl_down(v, 8);
        v += __shfl_down(v, 4);
        v += __shfl_down(v, 2);
        v += __shfl_down(v, 1);
        if (tid == 0) partials[blockIdx.x] = v;
    }
}

__global__ __launch_bounds__(512) void chamfer_final(
    const float* __restrict__ partials, float* __restrict__ out)
{
    __shared__ float red[512];
    const int tid = threadIdx.x;
    red[tid] = partials[tid];
    __syncthreads();
    if (tid < 64) {
        float v = 0.f;
        #pragma unroll
        for (int k = 0; k < 8; ++k) v += red[tid + 64 * k];
        v += __shfl_down(v, 32);
        v += __shfl_down(v, 16);
        v += __shfl_down(v, 8);
        v += __shfl_down(v, 4);
        v += __shfl_down(v, 2);
        v += __shfl_down(v, 1);
        // mean(d_t_to_x) + mean(d_x_to_t): both halves divide by B*4096 = 32768
        if (tid == 0) out[0] = v * (1.0f / 32768.0f);
    }
}

extern "C" void kernel_launch(void* const* d_in, const int* in_sizes, int n_in,
                              void* d_out, int out_size, void* d_ws, size_t ws_size,
                              hipStream_t stream) {
    const float* x   = (const float*)d_in[0];
    const float* tgt = (const float*)d_in[1];
    float* partials  = (float*)d_ws;   // 512 floats
    float* out       = (float*)d_out;  // 1 float

    chamfer_main<<<dim3(512), dim3(1024), 0, stream>>>(x, tgt, partials);
    chamfer_final<<<dim3(1), dim3(512), 0, stream>>>(partials, out);
}